// Round 4
// baseline (24551.855 us; speedup 1.0000x reference)
//
#include <hip/hip_runtime.h>
#include <hip/hip_bf16.h>
#include <math.h>

// ---------------- problem constants ----------------
#define B_        4096
#define ENC_STEPS 49     // SRC-1
#define TGT_      25
#define R_        1024
#define H_        67
#define I_        82
#define IP_       96     // input padded to multiple of 32
#define IP2_      192    // split-bf16 (hi|lo) doubled K
#define NG_       3072   // 3*R
#define FCN_      128    // fc output padded 67 -> 128
#define K2_       2048   // 2*R

typedef unsigned short u16;
typedef __attribute__((ext_vector_type(8))) short bf16x8_t;
typedef __attribute__((ext_vector_type(4))) float f32x4_t;

// ---------------- helpers ----------------
__device__ __forceinline__ float bf2f(u16 h) {
    union { unsigned int u; float f; } v; v.u = ((unsigned int)h) << 16; return v.f;
}
__device__ __forceinline__ u16 f2bf(float f) {
    union { unsigned int u; float f; } v; v.f = f;
    unsigned int u = v.u;
    u += 0x7fffu + ((u >> 16) & 1u);   // RNE
    return (u16)(u >> 16);
}
__device__ __forceinline__ float sigmf(float x) { return 1.f / (1.f + __expf(-x)); }
__device__ __forceinline__ float tanhfast(float x) { return 1.f - 2.f / (__expf(2.f * x) + 1.f); }

// async global->LDS, 16B per lane; LDS dest = wave-uniform base + lane*16 (required).
__device__ __forceinline__ void g2l16(const u16* g, u16* l) {
    __builtin_amdgcn_global_load_lds(
        (const __attribute__((address_space(1))) unsigned int*)(const void*)g,
        (__attribute__((address_space(3))) unsigned int*)(void*)l,
        16, 0, 0);
}

// ---------------- weight prep ----------------
__global__ void cast_bf16_kernel(const float* __restrict__ s, u16* __restrict__ d, int n) {
    int i = blockIdx.x * 256 + threadIdx.x;
    if (i < n) d[i] = f2bf(s[i]);
}
// Wi1 [3072,82] -> [3072,192] bf16: cols 0..95 padded Wi1, cols 96..191 duplicate (hi|lo split)
__global__ void pad_wi1_dup_kernel(const float* __restrict__ s, u16* __restrict__ d) {
    int i = blockIdx.x * 256 + threadIdx.x;
    if (i >= NG_ * IP2_) return;
    int r = i / IP2_, c = i % IP2_;
    int cc = (c < IP_) ? c : c - IP_;
    d[i] = (cc < I_) ? f2bf(s[r * I_ + cc]) : (u16)0;
}
// Wfc [67,2048] -> [128,2048] bf16, zero-padded N rows
__global__ void pad_wfc_kernel(const float* __restrict__ s, u16* __restrict__ d) {
    int i = blockIdx.x * 256 + threadIdx.x;
    if (i >= FCN_ * K2_) return;
    int r = i / K2_, c = i % K2_;
    d[i] = (r < H_) ? f2bf(s[r * K2_ + c]) : (u16)0;
}

// all encoder inputs -> xall bf16 [ENC][B][192] (hi|lo split), one launch
__global__ void pad_all_x_kernel(const float* __restrict__ enc, u16* __restrict__ xall) {
    int i = blockIdx.x * 256 + threadIdx.x;
    if (i >= B_ * ENC_STEPS * IP_) return;
    int c = i % IP_;
    int t = (i / IP_) % ENC_STEPS;
    int b = i / (IP_ * ENC_STEPS);
    float v = (c < I_) ? enc[((size_t)b * ENC_STEPS + t) * I_ + c] : 0.f;
    u16 hi = f2bf(v);
    u16 lo = f2bf(v - bf2f(hi));
    size_t base = ((size_t)t * B_ + b) * IP2_;
    xall[base + c]       = hi;
    xall[base + IP_ + c] = lo;
}

// decoder inp = concat(prev[:, :67], dec[:, t, 67:82]) -> xpad2 bf16 [B,192] (hi|lo)
__global__ void build_inp_kernel(const float* __restrict__ prev, int pstride,
                                 const float* __restrict__ dec, int t,
                                 u16* __restrict__ xpad) {
    int i = blockIdx.x * 256 + threadIdx.x;
    if (i >= B_ * IP_) return;
    int b = i / IP_, c = i % IP_;
    float v = 0.f;
    if (c < H_)      v = prev[(size_t)b * pstride + c];
    else if (c < I_) v = dec[((size_t)b * TGT_ + t) * I_ + c];
    u16 hi = f2bf(v);
    u16 lo = f2bf(v - bf2f(hi));
    xpad[(size_t)b * IP2_ + c]       = hi;
    xpad[(size_t)b * IP2_ + IP_ + c] = lo;
}

// ---------------- fused GRU step (one layer) ----------------
// Tile: 128 batch rows x 64 R-cols x 3 gates. Unified K-loop: x-pass (NX iters)
// then h-pass (32 iters). Double-buffered LDS: prefetch next K-tile right after
// the barrier, compute current -> vmcnt(0) drain at next barrier overlaps compute.
// LDS is K-major chunked (chunk = kchunk*rows + row): ds_read_b128 is 2-way-bank
// aliased only (free), and global_load_lds keeps its lane-contiguous dest.
// XCD swizzle: nb = 2*(lin%8) + ((lin>>3)&1) keeps each N-pair's weights in one XCD L2.
template<int KX>
__global__ __launch_bounds__(256, 2) void gru_step_kernel(
    const u16* __restrict__ Ax, int ldax,       // [B, ldax] bf16 input
    const u16* __restrict__ Wx,                 // [3R, KX] bf16
    const u16* __restrict__ Ah, int ldah,       // [B, ldah] bf16 state (cur)
    const u16* __restrict__ Wh,                 // [3R, 1024] bf16
    const float* __restrict__ bi, const float* __restrict__ bh,
    float* __restrict__ hf,                     // [B, R] fp32 state, in/out
    u16* __restrict__ hout)                     // bf16 state out (nxt buffer), row stride K2_
{
    constexpr int NX = KX / 32;
    constexpr int NH = R_ / 32;
    constexpr int NT = NX + NH;

    __shared__ __align__(16) u16 As[2 * 512 * 8];   // 2 x 8 KB
    __shared__ __align__(16) u16 Ws[2 * 768 * 8];   // 2 x 12 KB

    const int tid  = threadIdx.x;
    const int lane = tid & 63, wave = tid >> 6;
    const int wm = wave >> 1, wn = wave & 1;          // 2x2 waves: WM=64, WN=32
    const int lin = blockIdx.x + gridDim.x * blockIdx.y;      // 0..511
    const int nb  = ((lin & 7) << 1) | ((lin >> 3) & 1);      // 0..15
    const int mb  = lin >> 4;                                  // 0..31
    const int mbase = mb * 128;
    const int nbase = nb * 64;
    const int lr = lane & 15;
    const int kc = lane >> 4;                  // k-chunk 0..3 for fragment reads

    f32x4_t acc_r[4][2], acc_z[4][2], acc_xn[4][2], acc_hn[4][2];
#pragma unroll
    for (int i = 0; i < 4; i++)
#pragma unroll
        for (int j = 0; j < 2; j++) {
            acc_r[i][j]  = (f32x4_t){0,0,0,0};
            acc_z[i][j]  = (f32x4_t){0,0,0,0};
            acc_xn[i][j] = (f32x4_t){0,0,0,0};
            acc_hn[i][j] = (f32x4_t){0,0,0,0};
        }

    auto stage = [&](int it, int buf) {
        const u16* Asrc; int lda; const u16* Wsrc; int wk; int k0;
        if (it < NX) { Asrc = Ax; lda = ldax; Wsrc = Wx; wk = KX; k0 = it * 32; }
        else         { Asrc = Ah; lda = ldah; Wsrc = Wh; wk = R_; k0 = (it - NX) * 32; }
        u16* ab = As + buf * 4096;
        u16* wb = Ws + buf * 6144;
#pragma unroll
        for (int p = 0; p < 2; p++) {
            int g = tid + p * 256;                 // 512 chunks = 4 kchunks x 128 rows
            int kch = g >> 7, row = g & 127;
            g2l16(Asrc + (size_t)(mbase + row) * lda + k0 + kch * 8, ab + g * 8);
        }
#pragma unroll
        for (int p = 0; p < 3; p++) {
            int q = tid + p * 256;                 // 768 chunks = 4 kchunks x 192 rows
            int kch = q / 192, row = q % 192;
            int gate = row >> 6, rg = row & 63;
            g2l16(Wsrc + ((size_t)gate * R_ + nbase + rg) * wk + k0 + kch * 8, wb + q * 8);
        }
    };

    auto compute = [&](int it, int buf) {
        const u16* ab = As + buf * 4096;
        const u16* wb = Ws + buf * 6144;
        bf16x8_t a_f[4], w_r[2], w_z[2], w_n[2];
#pragma unroll
        for (int i = 0; i < 4; i++)
            a_f[i] = *(const bf16x8_t*)(ab + (kc * 128 + wm * 64 + i * 16 + lr) * 8);
#pragma unroll
        for (int j = 0; j < 2; j++) {
            int rw = wn * 32 + j * 16 + lr;
            w_r[j] = *(const bf16x8_t*)(wb + (kc * 192 + rw) * 8);
            w_z[j] = *(const bf16x8_t*)(wb + (kc * 192 + 64 + rw) * 8);
            w_n[j] = *(const bf16x8_t*)(wb + (kc * 192 + 128 + rw) * 8);
        }
        if (it < NX) {
#pragma unroll
            for (int i = 0; i < 4; i++)
#pragma unroll
                for (int j = 0; j < 2; j++) {
                    acc_r[i][j]  = __builtin_amdgcn_mfma_f32_16x16x32_bf16(a_f[i], w_r[j], acc_r[i][j], 0, 0, 0);
                    acc_z[i][j]  = __builtin_amdgcn_mfma_f32_16x16x32_bf16(a_f[i], w_z[j], acc_z[i][j], 0, 0, 0);
                    acc_xn[i][j] = __builtin_amdgcn_mfma_f32_16x16x32_bf16(a_f[i], w_n[j], acc_xn[i][j], 0, 0, 0);
                }
        } else {
#pragma unroll
            for (int i = 0; i < 4; i++)
#pragma unroll
                for (int j = 0; j < 2; j++) {
                    acc_r[i][j]  = __builtin_amdgcn_mfma_f32_16x16x32_bf16(a_f[i], w_r[j], acc_r[i][j], 0, 0, 0);
                    acc_z[i][j]  = __builtin_amdgcn_mfma_f32_16x16x32_bf16(a_f[i], w_z[j], acc_z[i][j], 0, 0, 0);
                    acc_hn[i][j] = __builtin_amdgcn_mfma_f32_16x16x32_bf16(a_f[i], w_n[j], acc_hn[i][j], 0, 0, 0);
                }
        }
    };

    stage(0, 0);
    for (int it = 0; it < NT; it++) {
        int buf = it & 1;
        __syncthreads();                 // drains loads for buf; prev reads of buf^1 done
        if (it + 1 < NT) stage(it + 1, buf ^ 1);
        compute(it, buf);
    }

    // ---- epilogue: gates + state update ----
    // C/D layout: col = lane&15, row = (lane>>4)*4 + reg   [HW-verified]
    const int rr2 = (lane >> 4) * 4;
#pragma unroll
    for (int j = 0; j < 2; j++) {
        const int col = nbase + wn * 32 + j * 16 + lr;
        const float b_ir = bi[col],          b_hr = bh[col];
        const float b_iz = bi[R_ + col],     b_hz = bh[R_ + col];
        const float b_in = bi[2 * R_ + col], b_hn = bh[2 * R_ + col];
#pragma unroll
        for (int i = 0; i < 4; i++) {
#pragma unroll
            for (int r = 0; r < 4; r++) {
                const int row = mbase + wm * 64 + i * 16 + rr2 + r;
                const float hold = hf[(size_t)row * R_ + col];
                const float rv = sigmf(acc_r[i][j][r] + b_ir + b_hr);
                const float zv = sigmf(acc_z[i][j][r] + b_iz + b_hz);
                const float nv = tanhfast(acc_xn[i][j][r] + b_in + rv * (acc_hn[i][j][r] + b_hn));
                const float hn = (1.f - zv) * nv + zv * hold;
                hf[(size_t)row * R_ + col] = hn;
                hout[(size_t)row * K2_ + col] = f2bf(hn);
            }
        }
    }
}

// ---------------- FC: 4-way K-split partial GEMM ----------------
__global__ __launch_bounds__(256) void fc_part_kernel(
    const u16* __restrict__ A, const u16* __restrict__ W, float* __restrict__ part) {
    __shared__ __align__(16) u16 As[64 * 32];     // 4 KB
    __shared__ __align__(16) u16 Bs[128 * 32];    // 8 KB
    const int tid  = threadIdx.x;
    const int lane = tid & 63, wave = tid >> 6;
    const int wm = wave >> 1, wn = wave & 1;      // WM=32, WN=64
    const int mbase = blockIdx.y * 64;
    const int kbase = blockIdx.x * 512;
    const int lr = lane & 15, kc = lane >> 4;

    f32x4_t acc[2][4];
#pragma unroll
    for (int i = 0; i < 2; i++)
#pragma unroll
        for (int j = 0; j < 4; j++) acc[i][j] = (f32x4_t){0, 0, 0, 0};

    for (int k0 = 0; k0 < 512; k0 += 32) {
        __syncthreads();
        {   // 256 chunks = 4 kchunks x 64 rows (K-major)
            int g = tid;
            int kch = g >> 6, row = g & 63;
            g2l16(A + (size_t)(mbase + row) * K2_ + kbase + k0 + kch * 8, As + g * 8);
        }
#pragma unroll
        for (int p = 0; p < 2; p++) {   // 512 chunks = 4 kchunks x 128 rows
            int q = tid + p * 256;
            int kch = q >> 7, row = q & 127;
            g2l16(W + (size_t)row * K2_ + kbase + k0 + kch * 8, Bs + q * 8);
        }
        __syncthreads();
        bf16x8_t a_f[2], b_f[4];
#pragma unroll
        for (int i = 0; i < 2; i++)
            a_f[i] = *(const bf16x8_t*)(As + (kc * 64 + wm * 32 + i * 16 + lr) * 8);
#pragma unroll
        for (int j = 0; j < 4; j++)
            b_f[j] = *(const bf16x8_t*)(Bs + (kc * 128 + wn * 64 + j * 16 + lr) * 8);
#pragma unroll
        for (int i = 0; i < 2; i++)
#pragma unroll
            for (int j = 0; j < 4; j++)
                acc[i][j] = __builtin_amdgcn_mfma_f32_16x16x32_bf16(a_f[i], b_f[j], acc[i][j], 0, 0, 0);
    }
    const int rr2 = (lane >> 4) * 4;
#pragma unroll
    for (int i = 0; i < 2; i++)
#pragma unroll
        for (int r = 0; r < 4; r++) {
            int row = mbase + wm * 32 + i * 16 + rr2 + r;
#pragma unroll
            for (int j = 0; j < 4; j++) {
                int col = wn * 64 + j * 16 + lr;
                part[((size_t)blockIdx.x * B_ + row) * FCN_ + col] = acc[i][j][r];
            }
        }
}

// out[:, t, :] = prev + sum(4 partials)[:, :67] + bfc  (deterministic reduce)
__global__ void fc_finish_kernel(const float* __restrict__ part, const float* __restrict__ prev,
                                 int pstride, const float* __restrict__ bfc,
                                 float* __restrict__ out, int t) {
    int i = blockIdx.x * 256 + threadIdx.x;
    if (i >= B_ * H_) return;
    int b = i / H_, c = i % H_;
    size_t idx = (size_t)b * FCN_ + c;
    const size_t S = (size_t)B_ * FCN_;
    float s = (part[idx] + part[S + idx]) + (part[2 * S + idx] + part[3 * S + idx]);
    out[((size_t)b * TGT_ + t) * H_ + c] = prev[(size_t)b * pstride + c] + s + bfc[c];
}

// ---------------- host launcher ----------------
extern "C" void kernel_launch(void* const* d_in, const int* in_sizes, int n_in,
                              void* d_out, int out_size, void* d_ws, size_t ws_size,
                              hipStream_t stream) {
    (void)in_sizes; (void)n_in; (void)out_size; (void)ws_size;
    const float* enc = (const float*)d_in[0];
    const float* dec = (const float*)d_in[1];
    const float* Wi1 = (const float*)d_in[2];
    const float* Wh1 = (const float*)d_in[3];
    const float* bi1 = (const float*)d_in[4];
    const float* bh1 = (const float*)d_in[5];
    const float* Wi2 = (const float*)d_in[6];
    const float* Wh2 = (const float*)d_in[7];
    const float* bi2 = (const float*)d_in[8];
    const float* bh2 = (const float*)d_in[9];
    const float* Wfc = (const float*)d_in[10];
    const float* bfc = (const float*)d_in[11];
    float* out = (float*)d_out;

    char* ws = (char*)d_ws;
    size_t off = 0;
    auto alloc = [&](size_t bytes) -> char* {
        char* p = ws + off;
        off += (bytes + 255) & ~(size_t)255;
        return p;
    };
    u16* Wh1b  = (u16*)alloc((size_t)NG_ * R_ * 2);
    u16* Wi2b  = (u16*)alloc((size_t)NG_ * R_ * 2);
    u16* Wh2b  = (u16*)alloc((size_t)NG_ * R_ * 2);
    u16* Wi1pb = (u16*)alloc((size_t)NG_ * IP2_ * 2);
    u16* Wfcb  = (u16*)alloc((size_t)FCN_ * K2_ * 2);
    // contiguous zero-init group: sbuf0, s1f, s2f
    u16* sbuf0 = (u16*)alloc((size_t)B_ * K2_ * 2);
    float* s1f = (float*)alloc((size_t)B_ * R_ * 4);
    float* s2f = (float*)alloc((size_t)B_ * R_ * 4);
    u16* sbuf1 = (u16*)alloc((size_t)B_ * K2_ * 2);
    u16* xall  = (u16*)alloc((size_t)ENC_STEPS * B_ * IP2_ * 2);
    u16* xpad2 = (u16*)alloc((size_t)B_ * IP2_ * 2);
    float* cfcp = (float*)alloc((size_t)4 * B_ * FCN_ * 4);
    u16* sbuf[2] = { sbuf0, sbuf1 };

    hipMemsetAsync(sbuf0, 0,
                   (size_t)B_ * K2_ * 2 + 2 * (size_t)B_ * R_ * 4, stream);

    // weight prep (rerun every call: ws re-poisoned)
    cast_bf16_kernel<<<(NG_ * R_ + 255) / 256, 256, 0, stream>>>(Wh1, Wh1b, NG_ * R_);
    cast_bf16_kernel<<<(NG_ * R_ + 255) / 256, 256, 0, stream>>>(Wi2, Wi2b, NG_ * R_);
    cast_bf16_kernel<<<(NG_ * R_ + 255) / 256, 256, 0, stream>>>(Wh2, Wh2b, NG_ * R_);
    pad_wi1_dup_kernel<<<(NG_ * IP2_ + 255) / 256, 256, 0, stream>>>(Wi1, Wi1pb);
    pad_wfc_kernel<<<(FCN_ * K2_ + 255) / 256, 256, 0, stream>>>(Wfc, Wfcb);
    pad_all_x_kernel<<<(B_ * ENC_STEPS * IP_ + 255) / 256, 256, 0, stream>>>(enc, xall);

    dim3 gru_grid(16, 32, 1);                  // 512 blocks (role-remapped in-kernel)
    dim3 fc_grid(4, B_ / 64, 1);               // 256 blocks
    const int binp_blocks = (B_ * IP_ + 255) / 256;
    const int fcf_blocks  = (B_ * H_ + 255) / 256;

    int phase = 0;

    // ---------------- encoder: 49 steps ----------------
    for (int t = 0; t < ENC_STEPS; t++) {
        u16* cur = sbuf[phase];
        u16* nxt = sbuf[phase ^ 1];
        gru_step_kernel<IP2_><<<gru_grid, 256, 0, stream>>>(
            xall + (size_t)t * B_ * IP2_, IP2_, Wi1pb,
            cur, K2_, Wh1b, bi1, bh1, s1f, nxt);
        gru_step_kernel<R_><<<gru_grid, 256, 0, stream>>>(
            nxt, K2_, Wi2b,
            cur + R_, K2_, Wh2b, bi2, bh2, s2f, nxt + R_);
        phase ^= 1;
    }

    // ---------------- decoder: 25 steps ----------------
    for (int t = 0; t < TGT_; t++) {
        const float* prev;
        int pstride;
        if (t == 0) { prev = dec;                 pstride = TGT_ * I_; }
        else        { prev = out + (t - 1) * H_;  pstride = TGT_ * H_; }
        u16* cur = sbuf[phase];
        u16* nxt = sbuf[phase ^ 1];
        build_inp_kernel<<<binp_blocks, 256, 0, stream>>>(prev, pstride, dec, t, xpad2);
        gru_step_kernel<IP2_><<<gru_grid, 256, 0, stream>>>(
            xpad2, IP2_, Wi1pb,
            cur, K2_, Wh1b, bi1, bh1, s1f, nxt);
        gru_step_kernel<R_><<<gru_grid, 256, 0, stream>>>(
            nxt, K2_, Wi2b,
            cur + R_, K2_, Wh2b, bi2, bh2, s2f, nxt + R_);
        fc_part_kernel<<<fc_grid, 256, 0, stream>>>(nxt, Wfcb, cfcp);
        fc_finish_kernel<<<fcf_blocks, 256, 0, stream>>>(cfcp, prev, pstride, bfc, out, t);
        phase ^= 1;
    }
}

// Round 5
// 13524.071 us; speedup vs baseline: 1.8154x; 1.8154x over previous
//
#include <hip/hip_runtime.h>
#include <hip/hip_bf16.h>
#include <math.h>

// ---------------- problem constants ----------------
#define B_        4096
#define ENC_STEPS 49     // SRC-1
#define TGT_      25
#define R_        1024
#define H_        67
#define I_        82
#define IP_       96     // input padded to multiple of 32
#define IP2_      192    // split-bf16 (hi|lo) doubled K
#define NG_       3072   // 3*R
#define FCN_      128    // fc output padded 67 -> 128
#define K2_       2048   // 2*R

typedef unsigned short u16;
typedef __attribute__((ext_vector_type(8))) short bf16x8_t;
typedef __attribute__((ext_vector_type(4))) float f32x4_t;

// ---------------- helpers ----------------
__device__ __forceinline__ float bf2f(u16 h) {
    union { unsigned int u; float f; } v; v.u = ((unsigned int)h) << 16; return v.f;
}
__device__ __forceinline__ u16 f2bf(float f) {
    union { unsigned int u; float f; } v; v.f = f;
    unsigned int u = v.u;
    u += 0x7fffu + ((u >> 16) & 1u);   // RNE
    return (u16)(u >> 16);
}
__device__ __forceinline__ float sigmf(float x) { return 1.f / (1.f + __expf(-x)); }
__device__ __forceinline__ float tanhfast(float x) { return 1.f - 2.f / (__expf(2.f * x) + 1.f); }

// async global->LDS, 16B per lane; LDS dest = wave-uniform base + lane*16 (required).
__device__ __forceinline__ void g2l16(const u16* g, u16* l) {
    __builtin_amdgcn_global_load_lds(
        (const __attribute__((address_space(1))) unsigned int*)(const void*)g,
        (__attribute__((address_space(3))) unsigned int*)(void*)l,
        16, 0, 0);
}

// ---------------- weight prep ----------------
__global__ void cast_bf16_kernel(const float* __restrict__ s, u16* __restrict__ d, int n) {
    int i = blockIdx.x * 256 + threadIdx.x;
    if (i < n) d[i] = f2bf(s[i]);
}
// Wi1 [3072,82] -> [3072,192] bf16: cols 0..95 padded Wi1, cols 96..191 duplicate (hi|lo split)
__global__ void pad_wi1_dup_kernel(const float* __restrict__ s, u16* __restrict__ d) {
    int i = blockIdx.x * 256 + threadIdx.x;
    if (i >= NG_ * IP2_) return;
    int r = i / IP2_, c = i % IP2_;
    int cc = (c < IP_) ? c : c - IP_;
    d[i] = (cc < I_) ? f2bf(s[r * I_ + cc]) : (u16)0;
}
// Wfc [67,2048] -> [128,2048] bf16, zero-padded N rows
__global__ void pad_wfc_kernel(const float* __restrict__ s, u16* __restrict__ d) {
    int i = blockIdx.x * 256 + threadIdx.x;
    if (i >= FCN_ * K2_) return;
    int r = i / K2_, c = i % K2_;
    d[i] = (r < H_) ? f2bf(s[r * K2_ + c]) : (u16)0;
}

// all encoder inputs -> xall bf16 [ENC][B][192] (hi|lo split), one launch
__global__ void pad_all_x_kernel(const float* __restrict__ enc, u16* __restrict__ xall) {
    int i = blockIdx.x * 256 + threadIdx.x;
    if (i >= B_ * ENC_STEPS * IP_) return;
    int c = i % IP_;
    int t = (i / IP_) % ENC_STEPS;
    int b = i / (IP_ * ENC_STEPS);
    float v = (c < I_) ? enc[((size_t)b * ENC_STEPS + t) * I_ + c] : 0.f;
    u16 hi = f2bf(v);
    u16 lo = f2bf(v - bf2f(hi));
    size_t base = ((size_t)t * B_ + b) * IP2_;
    xall[base + c]       = hi;
    xall[base + IP_ + c] = lo;
}

// decoder inp = concat(prev[:, :67], dec[:, t, 67:82]) -> xpad2 bf16 [B,192] (hi|lo)
__global__ void build_inp_kernel(const float* __restrict__ prev, int pstride,
                                 const float* __restrict__ dec, int t,
                                 u16* __restrict__ xpad) {
    int i = blockIdx.x * 256 + threadIdx.x;
    if (i >= B_ * IP_) return;
    int b = i / IP_, c = i % IP_;
    float v = 0.f;
    if (c < H_)      v = prev[(size_t)b * pstride + c];
    else if (c < I_) v = dec[((size_t)b * TGT_ + t) * I_ + c];
    u16 hi = f2bf(v);
    u16 lo = f2bf(v - bf2f(hi));
    xpad[(size_t)b * IP2_ + c]       = hi;
    xpad[(size_t)b * IP2_ + IP_ + c] = lo;
}

// ---------------- GRU step building blocks ----------------
// Stage one 32-wide K-tile of A (128 rows) into LDS, K-major chunked:
// chunk index g = kch*128 + row, dest = ab + g*8 elems (lane-contiguous).
__device__ __forceinline__ void gru_stage_a(const u16* __restrict__ src, int lda,
                                            int mbase, int k0, int tid, u16* ab) {
#pragma unroll
    for (int p = 0; p < 2; p++) {
        int g = tid + p * 256;                 // 512 chunks = 4 kchunks x 128 rows
        int kch = g >> 7, row = g & 127;
        g2l16(src + (size_t)(mbase + row) * lda + k0 + kch * 8, ab + g * 8);
    }
}
// Stage one 32-wide K-tile of W (3 gates x 64 rows) into LDS, K-major chunked.
__device__ __forceinline__ void gru_stage_w(const u16* __restrict__ src, int wk,
                                            int nbase, int k0, int tid, u16* wb) {
#pragma unroll
    for (int p = 0; p < 3; p++) {
        int q = tid + p * 256;                 // 768 chunks = 4 kchunks x 192 rows
        int kch = q / 192, row = q % 192;
        int gate = row >> 6, rg = row & 63;
        g2l16(src + ((size_t)gate * R_ + nbase + rg) * wk + k0 + kch * 8, wb + q * 8);
    }
}
// One 32-K MFMA block: 4x2 tiles x 3 gates; n-gate accumulator passed by caller
// (acc_xn for x-pass, acc_hn for h-pass).
__device__ __forceinline__ void gru_mfma(const u16* __restrict__ ab, const u16* __restrict__ wb,
                                         int kc, int lr, int wm, int wn,
                                         f32x4_t (&acc_r)[4][2], f32x4_t (&acc_z)[4][2],
                                         f32x4_t (&acc_n)[4][2]) {
    bf16x8_t a_f[4], w_r[2], w_z[2], w_n[2];
#pragma unroll
    for (int i = 0; i < 4; i++)
        a_f[i] = *(const bf16x8_t*)(ab + (kc * 128 + wm * 64 + i * 16 + lr) * 8);
#pragma unroll
    for (int j = 0; j < 2; j++) {
        int rw = wn * 32 + j * 16 + lr;
        w_r[j] = *(const bf16x8_t*)(wb + (kc * 192 + rw) * 8);
        w_z[j] = *(const bf16x8_t*)(wb + (kc * 192 + 64 + rw) * 8);
        w_n[j] = *(const bf16x8_t*)(wb + (kc * 192 + 128 + rw) * 8);
    }
#pragma unroll
    for (int i = 0; i < 4; i++)
#pragma unroll
        for (int j = 0; j < 2; j++) {
            acc_r[i][j] = __builtin_amdgcn_mfma_f32_16x16x32_bf16(a_f[i], w_r[j], acc_r[i][j], 0, 0, 0);
            acc_z[i][j] = __builtin_amdgcn_mfma_f32_16x16x32_bf16(a_f[i], w_z[j], acc_z[i][j], 0, 0, 0);
            acc_n[i][j] = __builtin_amdgcn_mfma_f32_16x16x32_bf16(a_f[i], w_n[j], acc_n[i][j], 0, 0, 0);
        }
}

// ---------------- fused GRU step (one layer) ----------------
// Tile: 128 batch rows x 64 R-cols x 3 gates. Two passes (x then h), each with a
// 2-tile double-buffered pipeline: barrier -> prefetch next tile into other buf ->
// compute current buf. Prefetch loads overlap the MFMA block; the next barrier's
// vmcnt(0) drain finds them mostly complete. All structure is compile-time
// (straight-line, no runtime source select) to keep accumulators in AGPRs (r4's
// lambda/runtime-branch version spilled 600 MB/dispatch to scratch).
template<int KX>
__global__ __launch_bounds__(256, 2) void gru_step_kernel(
    const u16* __restrict__ Ax, int ldax,       // [B, ldax] bf16 input
    const u16* __restrict__ Wx,                 // [3R, KX] bf16
    const u16* __restrict__ Ah, int ldah,       // [B, ldah] bf16 state (cur)
    const u16* __restrict__ Wh,                 // [3R, 1024] bf16
    const float* __restrict__ bi, const float* __restrict__ bh,
    float* __restrict__ hf,                     // [B, R] fp32 state, in/out
    u16* __restrict__ hout)                     // bf16 state out (nxt buffer), row stride K2_
{
    __shared__ __align__(16) u16 As[2 * 4096];   // 2 x 8 KB
    __shared__ __align__(16) u16 Ws[2 * 6144];   // 2 x 12 KB

    const int tid  = threadIdx.x;
    const int lane = tid & 63, wave = tid >> 6;
    const int wm = wave >> 1, wn = wave & 1;          // 2x2 waves: WM=64, WN=32
    const int lin = blockIdx.x + gridDim.x * blockIdx.y;      // 0..511
    const int nb  = ((lin & 7) << 1) | ((lin >> 3) & 1);      // XCD swizzle: 2 N-tiles/XCD
    const int mb  = lin >> 4;
    const int mbase = mb * 128;
    const int nbase = nb * 64;
    const int lr = lane & 15;
    const int kc = lane >> 4;                  // k-chunk 0..3 for fragment reads

    u16* As0 = As;      u16* As1 = As + 4096;
    u16* Ws0 = Ws;      u16* Ws1 = Ws + 6144;

    f32x4_t acc_r[4][2], acc_z[4][2], acc_xn[4][2], acc_hn[4][2];
#pragma unroll
    for (int i = 0; i < 4; i++)
#pragma unroll
        for (int j = 0; j < 2; j++) {
            acc_r[i][j]  = (f32x4_t){0,0,0,0};
            acc_z[i][j]  = (f32x4_t){0,0,0,0};
            acc_xn[i][j] = (f32x4_t){0,0,0,0};
            acc_hn[i][j] = (f32x4_t){0,0,0,0};
        }

    // ---- pass 1: x @ Wx^T (KX), pipelined 2 tiles/iter ----
    gru_stage_a(Ax, ldax, mbase, 0, tid, As0);
    gru_stage_w(Wx, KX, nbase, 0, tid, Ws0);
#pragma unroll 1
    for (int k0 = 0; k0 < KX; k0 += 64) {
        __syncthreads();                                   // tile k0 (buf0) ready
        if (k0 + 32 < KX) {
            gru_stage_a(Ax, ldax, mbase, k0 + 32, tid, As1);
            gru_stage_w(Wx, KX, nbase, k0 + 32, tid, Ws1);
        }
        gru_mfma(As0, Ws0, kc, lr, wm, wn, acc_r, acc_z, acc_xn);
        __syncthreads();                                   // tile k0+32 (buf1) ready
        if (k0 + 64 < KX) {
            gru_stage_a(Ax, ldax, mbase, k0 + 64, tid, As0);
            gru_stage_w(Wx, KX, nbase, k0 + 64, tid, Ws0);
        } else {
            gru_stage_a(Ah, ldah, mbase, 0, tid, As0);     // prefetch h-pass tile 0
            gru_stage_w(Wh, R_, nbase, 0, tid, Ws0);
        }
        gru_mfma(As1, Ws1, kc, lr, wm, wn, acc_r, acc_z, acc_xn);
    }

    // ---- pass 2: h_old @ Wh^T (1024), tile 0 already in flight to buf0 ----
#pragma unroll 1
    for (int k0 = 0; k0 < R_; k0 += 64) {
        __syncthreads();
        if (k0 + 32 < R_) {
            gru_stage_a(Ah, ldah, mbase, k0 + 32, tid, As1);
            gru_stage_w(Wh, R_, nbase, k0 + 32, tid, Ws1);
        }
        gru_mfma(As0, Ws0, kc, lr, wm, wn, acc_r, acc_z, acc_hn);
        __syncthreads();
        if (k0 + 64 < R_) {
            gru_stage_a(Ah, ldah, mbase, k0 + 64, tid, As0);
            gru_stage_w(Wh, R_, nbase, k0 + 64, tid, Ws0);
        }
        gru_mfma(As1, Ws1, kc, lr, wm, wn, acc_r, acc_z, acc_hn);
    }

    // ---- epilogue: gates + state update ----
    // C/D layout: col = lane&15, row = (lane>>4)*4 + reg   [HW-verified]
    const int rr2 = (lane >> 4) * 4;
#pragma unroll
    for (int j = 0; j < 2; j++) {
        const int col = nbase + wn * 32 + j * 16 + lr;
        const float b_ir = bi[col],          b_hr = bh[col];
        const float b_iz = bi[R_ + col],     b_hz = bh[R_ + col];
        const float b_in = bi[2 * R_ + col], b_hn = bh[2 * R_ + col];
#pragma unroll
        for (int i = 0; i < 4; i++) {
#pragma unroll
            for (int r = 0; r < 4; r++) {
                const int row = mbase + wm * 64 + i * 16 + rr2 + r;
                const float hold = hf[(size_t)row * R_ + col];
                const float rv = sigmf(acc_r[i][j][r] + b_ir + b_hr);
                const float zv = sigmf(acc_z[i][j][r] + b_iz + b_hz);
                const float nv = tanhfast(acc_xn[i][j][r] + b_in + rv * (acc_hn[i][j][r] + b_hn));
                const float hn = (1.f - zv) * nv + zv * hold;
                hf[(size_t)row * R_ + col] = hn;
                hout[(size_t)row * K2_ + col] = f2bf(hn);
            }
        }
    }
}

// ---------------- FC: 4-way K-split partial GEMM ----------------
__global__ __launch_bounds__(256) void fc_part_kernel(
    const u16* __restrict__ A, const u16* __restrict__ W, float* __restrict__ part) {
    __shared__ __align__(16) u16 As[64 * 32];     // 4 KB
    __shared__ __align__(16) u16 Bs[128 * 32];    // 8 KB
    const int tid  = threadIdx.x;
    const int lane = tid & 63, wave = tid >> 6;
    const int wm = wave >> 1, wn = wave & 1;      // WM=32, WN=64
    const int mbase = blockIdx.y * 64;
    const int kbase = blockIdx.x * 512;
    const int lr = lane & 15, kc = lane >> 4;

    f32x4_t acc[2][4];
#pragma unroll
    for (int i = 0; i < 2; i++)
#pragma unroll
        for (int j = 0; j < 4; j++) acc[i][j] = (f32x4_t){0, 0, 0, 0};

    for (int k0 = 0; k0 < 512; k0 += 32) {
        __syncthreads();
        {   // 256 chunks = 4 kchunks x 64 rows (K-major)
            int g = tid;
            int kch = g >> 6, row = g & 63;
            g2l16(A + (size_t)(mbase + row) * K2_ + kbase + k0 + kch * 8, As + g * 8);
        }
#pragma unroll
        for (int p = 0; p < 2; p++) {   // 512 chunks = 4 kchunks x 128 rows
            int q = tid + p * 256;
            int kch = q >> 7, row = q & 127;
            g2l16(W + (size_t)row * K2_ + kbase + k0 + kch * 8, Bs + q * 8);
        }
        __syncthreads();
        bf16x8_t a_f[2], b_f[4];
#pragma unroll
        for (int i = 0; i < 2; i++)
            a_f[i] = *(const bf16x8_t*)(As + (kc * 64 + wm * 32 + i * 16 + lr) * 8);
#pragma unroll
        for (int j = 0; j < 4; j++)
            b_f[j] = *(const bf16x8_t*)(Bs + (kc * 128 + wn * 64 + j * 16 + lr) * 8);
#pragma unroll
        for (int i = 0; i < 2; i++)
#pragma unroll
            for (int j = 0; j < 4; j++)
                acc[i][j] = __builtin_amdgcn_mfma_f32_16x16x32_bf16(a_f[i], b_f[j], acc[i][j], 0, 0, 0);
    }
    const int rr2 = (lane >> 4) * 4;
#pragma unroll
    for (int i = 0; i < 2; i++)
#pragma unroll
        for (int r = 0; r < 4; r++) {
            int row = mbase + wm * 32 + i * 16 + rr2 + r;
#pragma unroll
            for (int j = 0; j < 4; j++) {
                int col = wn * 64 + j * 16 + lr;
                part[((size_t)blockIdx.x * B_ + row) * FCN_ + col] = acc[i][j][r];
            }
        }
}

// out[:, t, :] = prev + sum(4 partials)[:, :67] + bfc  (deterministic reduce)
__global__ void fc_finish_kernel(const float* __restrict__ part, const float* __restrict__ prev,
                                 int pstride, const float* __restrict__ bfc,
                                 float* __restrict__ out, int t) {
    int i = blockIdx.x * 256 + threadIdx.x;
    if (i >= B_ * H_) return;
    int b = i / H_, c = i % H_;
    size_t idx = (size_t)b * FCN_ + c;
    const size_t S = (size_t)B_ * FCN_;
    float s = (part[idx] + part[S + idx]) + (part[2 * S + idx] + part[3 * S + idx]);
    out[((size_t)b * TGT_ + t) * H_ + c] = prev[(size_t)b * pstride + c] + s + bfc[c];
}

// ---------------- host launcher ----------------
extern "C" void kernel_launch(void* const* d_in, const int* in_sizes, int n_in,
                              void* d_out, int out_size, void* d_ws, size_t ws_size,
                              hipStream_t stream) {
    (void)in_sizes; (void)n_in; (void)out_size; (void)ws_size;
    const float* enc = (const float*)d_in[0];
    const float* dec = (const float*)d_in[1];
    const float* Wi1 = (const float*)d_in[2];
    const float* Wh1 = (const float*)d_in[3];
    const float* bi1 = (const float*)d_in[4];
    const float* bh1 = (const float*)d_in[5];
    const float* Wi2 = (const float*)d_in[6];
    const float* Wh2 = (const float*)d_in[7];
    const float* bi2 = (const float*)d_in[8];
    const float* bh2 = (const float*)d_in[9];
    const float* Wfc = (const float*)d_in[10];
    const float* bfc = (const float*)d_in[11];
    float* out = (float*)d_out;

    char* ws = (char*)d_ws;
    size_t off = 0;
    auto alloc = [&](size_t bytes) -> char* {
        char* p = ws + off;
        off += (bytes + 255) & ~(size_t)255;
        return p;
    };
    u16* Wh1b  = (u16*)alloc((size_t)NG_ * R_ * 2);
    u16* Wi2b  = (u16*)alloc((size_t)NG_ * R_ * 2);
    u16* Wh2b  = (u16*)alloc((size_t)NG_ * R_ * 2);
    u16* Wi1pb = (u16*)alloc((size_t)NG_ * IP2_ * 2);
    u16* Wfcb  = (u16*)alloc((size_t)FCN_ * K2_ * 2);
    // contiguous zero-init group: sbuf0, s1f, s2f
    u16* sbuf0 = (u16*)alloc((size_t)B_ * K2_ * 2);
    float* s1f = (float*)alloc((size_t)B_ * R_ * 4);
    float* s2f = (float*)alloc((size_t)B_ * R_ * 4);
    u16* sbuf1 = (u16*)alloc((size_t)B_ * K2_ * 2);
    u16* xall  = (u16*)alloc((size_t)ENC_STEPS * B_ * IP2_ * 2);
    u16* xpad2 = (u16*)alloc((size_t)B_ * IP2_ * 2);
    float* cfcp = (float*)alloc((size_t)4 * B_ * FCN_ * 4);
    u16* sbuf[2] = { sbuf0, sbuf1 };

    hipMemsetAsync(sbuf0, 0,
                   (size_t)B_ * K2_ * 2 + 2 * (size_t)B_ * R_ * 4, stream);

    // weight prep (rerun every call: ws re-poisoned)
    cast_bf16_kernel<<<(NG_ * R_ + 255) / 256, 256, 0, stream>>>(Wh1, Wh1b, NG_ * R_);
    cast_bf16_kernel<<<(NG_ * R_ + 255) / 256, 256, 0, stream>>>(Wi2, Wi2b, NG_ * R_);
    cast_bf16_kernel<<<(NG_ * R_ + 255) / 256, 256, 0, stream>>>(Wh2, Wh2b, NG_ * R_);
    pad_wi1_dup_kernel<<<(NG_ * IP2_ + 255) / 256, 256, 0, stream>>>(Wi1, Wi1pb);
    pad_wfc_kernel<<<(FCN_ * K2_ + 255) / 256, 256, 0, stream>>>(Wfc, Wfcb);
    pad_all_x_kernel<<<(B_ * ENC_STEPS * IP_ + 255) / 256, 256, 0, stream>>>(enc, xall);

    dim3 gru_grid(16, 32, 1);                  // 512 blocks (role-remapped in-kernel)
    dim3 fc_grid(4, B_ / 64, 1);               // 256 blocks
    const int binp_blocks = (B_ * IP_ + 255) / 256;
    const int fcf_blocks  = (B_ * H_ + 255) / 256;

    int phase = 0;

    // ---------------- encoder: 49 steps ----------------
    for (int t = 0; t < ENC_STEPS; t++) {
        u16* cur = sbuf[phase];
        u16* nxt = sbuf[phase ^ 1];
        gru_step_kernel<IP2_><<<gru_grid, 256, 0, stream>>>(
            xall + (size_t)t * B_ * IP2_, IP2_, Wi1pb,
            cur, K2_, Wh1b, bi1, bh1, s1f, nxt);
        gru_step_kernel<R_><<<gru_grid, 256, 0, stream>>>(
            nxt, K2_, Wi2b,
            cur + R_, K2_, Wh2b, bi2, bh2, s2f, nxt + R_);
        phase ^= 1;
    }

    // ---------------- decoder: 25 steps ----------------
    for (int t = 0; t < TGT_; t++) {
        const float* prev;
        int pstride;
        if (t == 0) { prev = dec;                 pstride = TGT_ * I_; }
        else        { prev = out + (t - 1) * H_;  pstride = TGT_ * H_; }
        u16* cur = sbuf[phase];
        u16* nxt = sbuf[phase ^ 1];
        build_inp_kernel<<<binp_blocks, 256, 0, stream>>>(prev, pstride, dec, t, xpad2);
        gru_step_kernel<IP2_><<<gru_grid, 256, 0, stream>>>(
            xpad2, IP2_, Wi1pb,
            cur, K2_, Wh1b, bi1, bh1, s1f, nxt);
        gru_step_kernel<R_><<<gru_grid, 256, 0, stream>>>(
            nxt, K2_, Wi2b,
            cur + R_, K2_, Wh2b, bi2, bh2, s2f, nxt + R_);
        fc_part_kernel<<<fc_grid, 256, 0, stream>>>(nxt, Wfcb, cfcp);
        fc_finish_kernel<<<fcf_blocks, 256, 0, stream>>>(cfcp, prev, pstride, bfc, out, t);
        phase ^= 1;
    }
}